// Round 2
// baseline (65.541 us; speedup 1.0000x reference)
//
#include <hip/hip_runtime.h>

// Active-set water-filling projection, one 64-lane wave per row (B=2048, N=1024).
//
// Phase-faithful to the reference (never-unclamp, phase 0 lows then phase 1
// highs, fused transition), but reformulated around a single certificate:
// within each phase t is monotone, so clamp sets are NESTED, and the alive
// count B strictly decreases iff new violators appeared. Therefore:
//   - convergence / phase-advance test == (B == prevB)   [pure SALU]
//   - no per-element violator re-scan, no __any ballot-vote
//   - B itself comes from per-slot v_cmp + s_bcnt1 (ballot/popcll), which
//     co-issues on the scalar pipe under the VALU sum-scan -> the second
//     DPP reduction chain of the old kernel disappears.
// Unified round for both phases:  clamped(k) <=> v_k < Tc
//   phase 0: v=y,   w=0, Tc=-t   (y+t<0   <=> y   < -t)
//   phase 1: v=u-y, w=u, Tc=+t   (y+t>u   <=> u-y <  t), lows frozen as
//            (v=-3e38, w=0): always "clamped at upper 0" -> contribute 0.
// Per-phase fixed points are unique roots of monotone piecewise-linear
// equations (phase0: sum max(y+t,0)=C; phase1: sum_{not L} min(y+t,u)=C),
// so any monotone iteration reaching them matches the reference output.
//
// Everything per-lane is a NAMED SCALAR (no arrays, no address-taking).

#define N_COLS 1024
#define NBIKES 512.0f

#define DPP_ADD(ctrl) \
    a += __int_as_float(__builtin_amdgcn_update_dpp(0, __float_as_int(a), (ctrl), 0xf, 0xf, true));

// Full 64-lane sum, result broadcast to all lanes.
__device__ __forceinline__ float wave_sum_bcast(float a) {
    DPP_ADD(0x111)   // row_shr:1
    DPP_ADD(0x112)   // row_shr:2
    DPP_ADD(0x114)   // row_shr:4
    DPP_ADD(0x118)   // row_shr:8  -> lanes 15/31/47/63 hold row-of-16 sums
    DPP_ADD(0x142)   // row_bcast:15
    DPP_ADD(0x143)   // row_bcast:31 -> lane 63 = full wave sum
    return __int_as_float(__builtin_amdgcn_readlane(__float_as_int(a), 63));
}

#define FOREACH16(OP) OP(0) OP(1) OP(2) OP(3) OP(4) OP(5) OP(6) OP(7) \
                      OP(8) OP(9) OP(10) OP(11) OP(12) OP(13) OP(14) OP(15)

__global__ __launch_bounds__(256) void proj_rows(
    const float* __restrict__ y,
    const float* __restrict__ upper,
    float* __restrict__ out,
    int B)
{
    const int lane = threadIdx.x & 63;
    const int wave = threadIdx.x >> 6;
    const int row  = (blockIdx.x << 2) + wave;
    if (row >= B) return;

    const float* yrow = y + (size_t)row * N_COLS;
    const int col = lane << 2;

    // Each lane owns 16 elements: element = j*256 + 4*lane + k.
    const float4 Y0 = *reinterpret_cast<const float4*>(yrow + col);
    const float4 Y1 = *reinterpret_cast<const float4*>(yrow + 256 + col);
    const float4 Y2 = *reinterpret_cast<const float4*>(yrow + 512 + col);
    const float4 Y3 = *reinterpret_cast<const float4*>(yrow + 768 + col);
    const float4 U0 = *reinterpret_cast<const float4*>(upper + col);
    const float4 U1 = *reinterpret_cast<const float4*>(upper + 256 + col);
    const float4 U2 = *reinterpret_cast<const float4*>(upper + 512 + col);
    const float4 U3 = *reinterpret_cast<const float4*>(upper + 768 + col);

    float y0 = Y0.x, y1 = Y0.y, y2  = Y0.z, y3  = Y0.w;
    float y4 = Y1.x, y5 = Y1.y, y6  = Y1.z, y7  = Y1.w;
    float y8 = Y2.x, y9 = Y2.y, y10 = Y2.z, y11 = Y2.w;
    float y12 = Y3.x, y13 = Y3.y, y14 = Y3.z, y15 = Y3.w;
    float u0 = U0.x, u1 = U0.y, u2  = U0.z, u3  = U0.w;
    float u4 = U1.x, u5 = U1.y, u6  = U1.z, u7  = U1.w;
    float u8 = U2.x, u9 = U2.y, u10 = U2.z, u11 = U2.w;
    float u12 = U3.x, u13 = U3.y, u14 = U3.z, u15 = U3.w;

    // Unified-round state: test value v, clamp value w (phase 0: v=y, w=0).
    float v0 = y0, v1 = y1, v2  = y2,  v3  = y3,
          v4 = y4, v5 = y5, v6  = y6,  v7  = y7,
          v8 = y8, v9 = y9, v10 = y10, v11 = y11,
          v12 = y12, v13 = y13, v14 = y14, v15 = y15;
    float w0 = 0.f, w1 = 0.f, w2 = 0.f, w3 = 0.f, w4 = 0.f, w5 = 0.f,
          w6 = 0.f, w7 = 0.f, w8 = 0.f, w9 = 0.f, w10 = 0.f, w11 = 0.f,
          w12 = 0.f, w13 = 0.f, w14 = 0.f, w15 = 0.f;
    bool c0 = false, c1 = false, c2 = false, c3 = false, c4 = false,
         c5 = false, c6 = false, c7 = false, c8 = false, c9 = false,
         c10 = false, c11 = false, c12 = false, c13 = false, c14 = false,
         c15 = false;

    float t = 1.0e38f;                 // Tc = -1e38 in round 1 -> all alive
    int sgnmask = (int)0x80000000;     // phase 0: Tc = -t; phase 1: Tc = +t
    int prevB = -1;
    bool done = false;

    for (int it = 0; it < 40 && !done; ++it) {
        const float Tc = __int_as_float(__float_as_int(t) ^ sgnmask);

        // clamp test per slot (one v_cmp each; mask reused by popcll AND cndmask)
#define CMPc(i) c##i = (v##i < Tc);
        FOREACH16(CMPc)

        // alive count on the scalar pipe (s_bcnt1 chains, co-issue with VALU)
        int nc = 0;
#define CNT(i) nc += (int)__popcll(__ballot((int)c##i));
        FOREACH16(CNT)
        const int Bcnt = 1024 - nc;

        // A = sum(clamped ? w : y) over the wave; 4 ILP accumulator chains
        float aA = 0.f, aB = 0.f, aC = 0.f, aD = 0.f;
        aA += c0  ? w0  : y0;   aB += c1  ? w1  : y1;
        aC += c2  ? w2  : y2;   aD += c3  ? w3  : y3;
        aA += c4  ? w4  : y4;   aB += c5  ? w5  : y5;
        aC += c6  ? w6  : y6;   aD += c7  ? w7  : y7;
        aA += c8  ? w8  : y8;   aB += c9  ? w9  : y9;
        aC += c10 ? w10 : y10;  aD += c11 ? w11 : y11;
        aA += c12 ? w12 : y12;  aB += c13 ? w13 : y13;
        aC += c14 ? w14 : y14;  aD += c15 ? w15 : y15;
        float a = (aA + aB) + (aC + aD);
        const float A = wave_sum_bcast(a);

        t = (NBIKES - A) * __builtin_amdgcn_rcpf((float)(Bcnt > 0 ? Bcnt : 1));

        if (Bcnt == prevB) {
            // No new violators: t just recomputed to the identical value.
            if (sgnmask == 0) {
                done = true;                       // phase 1 converged
            } else {
                // Fused phase transition (same t): freeze lows (c == low set,
                // valid since t is unchanged this round). prevB stays == Bcnt:
                // if no upper violators, next round's B equals it -> exit with
                // the same t, matching the reference's fused behavior.
                sgnmask = 0;
#define TRANS(i) v##i = c##i ? -3.0e38f : (u##i - y##i); \
                 w##i = c##i ? 0.f : u##i;
                FOREACH16(TRANS)
            }
        } else {
            prevB = Bcnt;
        }
    }

    // Output: clamp masks c and t are from the final (converged) round.
    // phase 1: c ? w : y+t  (lows: w=0, highs: w=u). If (unreachable) the loop
    // exhausted in phase 0, c is the low set and w=0 -> c ? 0 : y+t, correct.
    float* orow = out + (size_t)row * N_COLS;
    float4 O;
    O.x = c0  ? w0  : y0  + t;
    O.y = c1  ? w1  : y1  + t;
    O.z = c2  ? w2  : y2  + t;
    O.w = c3  ? w3  : y3  + t;
    *reinterpret_cast<float4*>(orow + col) = O;
    O.x = c4  ? w4  : y4  + t;
    O.y = c5  ? w5  : y5  + t;
    O.z = c6  ? w6  : y6  + t;
    O.w = c7  ? w7  : y7  + t;
    *reinterpret_cast<float4*>(orow + 256 + col) = O;
    O.x = c8  ? w8  : y8  + t;
    O.y = c9  ? w9  : y9  + t;
    O.z = c10 ? w10 : y10 + t;
    O.w = c11 ? w11 : y11 + t;
    *reinterpret_cast<float4*>(orow + 512 + col) = O;
    O.x = c12 ? w12 : y12 + t;
    O.y = c13 ? w13 : y13 + t;
    O.z = c14 ? w14 : y14 + t;
    O.w = c15 ? w15 : y15 + t;
    *reinterpret_cast<float4*>(orow + 768 + col) = O;
}

extern "C" void kernel_launch(void* const* d_in, const int* in_sizes, int n_in,
                              void* d_out, int out_size, void* d_ws, size_t ws_size,
                              hipStream_t stream) {
    const float* yv    = (const float*)d_in[0];
    const float* upper = (const float*)d_in[1];
    float* out = (float*)d_out;
    const int B = in_sizes[0] / N_COLS;        // 2048
    const int blocks = (B + 3) >> 2;           // 4 rows (waves) per 256-thread block
    proj_rows<<<blocks, 256, 0, stream>>>(yv, upper, out, B);
}